// Round 7
// baseline (568.774 us; speedup 1.0000x reference)
//
#include <hip/hip_runtime.h>
#include <hip/hip_bf16.h>

#define PP 8192
#define UU 4096
#define EE 4096
#define BB 1024

using f32x4  = __attribute__((ext_vector_type(4))) float;
using u32x4  = __attribute__((ext_vector_type(4))) unsigned int;
using bf16x8 = __attribute__((ext_vector_type(8))) short;
typedef __hip_bfloat16 bf16_t;

__device__ __forceinline__ unsigned cvt2(float a, float b){
  unsigned r;
  asm("v_cvt_pk_bf16_f32 %0, %1, %2" : "=v"(r) : "v"(a), "v"(b));
  return r;
}

__device__ __forceinline__ void gload16(const void* g, void* l){
  __builtin_amdgcn_global_load_lds((const __attribute__((address_space(1))) void*)g,
                                   (__attribute__((address_space(3))) void*)l, 16, 0, 0);
}

struct Job {
  const float*  A;      // [M][K] f32
  const bf16_t* Bt;     // [128][K] bf16 (B transposed)
  const float*  add;    // epilogue add; may be null
  const float*  bvec;   // sigmoid bias [128]; null otherwise
  float*        outF;   // f32 out [M][128]; may be null
  bf16_t*       outT;   // transposed bf16 out [128][stride]; may be null
  int           outTstride;
  float         scale;
  int           K;
  int           nb;     // number of row tiles (16-row tiles for gemm_stream, 32 for gates)
  int           mode;   // 0 linear, 1 sigmoid-gate
};

#define WAITV(n) asm volatile("s_waitcnt vmcnt(" #n ")" ::: "memory")
#define SBAR __builtin_amdgcn_sched_barrier(0)

// =============== STREAM GEMM: zero LDS / zero barriers in main loop ===============
// Block 256 thr = 4 waves: wh = wid&1 (K half), wn = wid>>1 (64-col half).
// Each wave: 16 rows x 64 cols x K/2, A and B streamed to registers, 2-deep pipeline.
__global__ __launch_bounds__(256, 3) void gemm_stream(Job j0, Job j1, Job j2){
  __shared__ float lds[4][16][64];
  __shared__ float fin[16][128];
  int bid = blockIdx.x;
  Job j = j0;
  if (bid >= j.nb){ bid -= j.nb; j = j1; if (bid >= j.nb){ bid -= j.nb; j = j2; } }
  const int K = j.K;
  const int S = K >> 7;                 // 64-k steps per wave (wave covers K/2)
  const int m0 = bid << 4;
  const int tid = threadIdx.x;
  const int lane = tid & 63;
  const int wid = tid >> 6;
  const int wh = wid & 1, wn = wid >> 1;

  // ---- A stream: lane row = lane&15; per step 256B/row, loads at +0,+16,+128,+144 ----
  const char* apE = (const char*)j.A
      + (size_t)(m0 + (lane & 15)) * (size_t)K * 4
      + (size_t)wh * (size_t)K * 2            // wh * (K/2) * 4B
      + (unsigned)((lane >> 4) << 5);
  const char* apO = apE + 256;

  // ---- B stream: 4 fragment pointers (n0), per step 128B/row, loads at +0,+64 ----
  const char* bp_base = (const char*)j.Bt + (size_t)wh * (size_t)K; // wh*(K/2)*2B
  const char* bpE0, *bpE1, *bpE2, *bpE3, *bpO0, *bpO1, *bpO2, *bpO3;
  {
    unsigned lo = (unsigned)((lane >> 4) << 4);
    int n0b = wn * 64 + (lane & 15);
    bpE0 = bp_base + (size_t)(n0b     ) * (size_t)K * 2 + lo;
    bpE1 = bp_base + (size_t)(n0b + 16) * (size_t)K * 2 + lo;
    bpE2 = bp_base + (size_t)(n0b + 32) * (size_t)K * 2 + lo;
    bpE3 = bp_base + (size_t)(n0b + 48) * (size_t)K * 2 + lo;
    bpO0 = bpE0 + 128; bpO1 = bpE1 + 128; bpO2 = bpE2 + 128; bpO3 = bpE3 + 128;
  }

  f32x4 aE0, aE1, aE2, aE3, aO0, aO1, aO2, aO3;
  bf16x8 bE0h0,bE0h1,bE1h0,bE1h1,bE2h0,bE2h1,bE3h0,bE3h1;
  bf16x8 bO0h0,bO0h1,bO1h0,bO1h1,bO2h0,bO2h1,bO3h0,bO3h1;

  f32x4 acc0 = {0.f,0.f,0.f,0.f}, acc1 = acc0, acc2 = acc0, acc3 = acc0;

#define ISSUE_A(a0,a1,a2,a3,p) do { \
    asm volatile("global_load_dwordx4 %0, %4, off\n\t" \
                 "global_load_dwordx4 %1, %4, off offset:16\n\t" \
                 "global_load_dwordx4 %2, %4, off offset:128\n\t" \
                 "global_load_dwordx4 %3, %4, off offset:144" \
      : "=&v"(a0),"=&v"(a1),"=&v"(a2),"=&v"(a3) : "v"(p) : "memory"); \
    p += 512; } while(0)
#define ISSUE_B1(b0,b1,p) do { \
    asm volatile("global_load_dwordx4 %0, %2, off\n\t" \
                 "global_load_dwordx4 %1, %2, off offset:64" \
      : "=&v"(b0),"=&v"(b1) : "v"(p) : "memory"); \
    p += 256; } while(0)

#define ISSUE_E() do { ISSUE_A(aE0,aE1,aE2,aE3,apE); \
    ISSUE_B1(bE0h0,bE0h1,bpE0); ISSUE_B1(bE1h0,bE1h1,bpE1); \
    ISSUE_B1(bE2h0,bE2h1,bpE2); ISSUE_B1(bE3h0,bE3h1,bpE3); } while(0)
#define ISSUE_O() do { ISSUE_A(aO0,aO1,aO2,aO3,apO); \
    ISSUE_B1(bO0h0,bO0h1,bpO0); ISSUE_B1(bO1h0,bO1h1,bpO1); \
    ISSUE_B1(bO2h0,bO2h1,bpO2); ISSUE_B1(bO3h0,bO3h1,bpO3); } while(0)

#define COMP(a0,a1,a2,a3,b0h0,b0h1,b1h0,b1h1,b2h0,b2h1,b3h0,b3h1) do { \
    union { bf16x8 v; unsigned u[4]; } p0, p1; \
    p0.u[0] = cvt2(a0.x, a0.y); p0.u[1] = cvt2(a0.z, a0.w); \
    p0.u[2] = cvt2(a1.x, a1.y); p0.u[3] = cvt2(a1.z, a1.w); \
    p1.u[0] = cvt2(a2.x, a2.y); p1.u[1] = cvt2(a2.z, a2.w); \
    p1.u[2] = cvt2(a3.x, a3.y); p1.u[3] = cvt2(a3.z, a3.w); \
    acc0 = __builtin_amdgcn_mfma_f32_16x16x32_bf16(p0.v, b0h0, acc0, 0,0,0); \
    acc1 = __builtin_amdgcn_mfma_f32_16x16x32_bf16(p0.v, b1h0, acc1, 0,0,0); \
    acc2 = __builtin_amdgcn_mfma_f32_16x16x32_bf16(p0.v, b2h0, acc2, 0,0,0); \
    acc3 = __builtin_amdgcn_mfma_f32_16x16x32_bf16(p0.v, b3h0, acc3, 0,0,0); \
    acc0 = __builtin_amdgcn_mfma_f32_16x16x32_bf16(p1.v, b0h1, acc0, 0,0,0); \
    acc1 = __builtin_amdgcn_mfma_f32_16x16x32_bf16(p1.v, b1h1, acc1, 0,0,0); \
    acc2 = __builtin_amdgcn_mfma_f32_16x16x32_bf16(p1.v, b2h1, acc2, 0,0,0); \
    acc3 = __builtin_amdgcn_mfma_f32_16x16x32_bf16(p1.v, b3h1, acc3, 0,0,0); } while(0)

  ISSUE_E();   // step 0 data (12 loads)
  ISSUE_O();   // step 1 data (12 loads)

  for (int t = 0; t < S; t += 2){
    WAITV(12); SBAR;   // E(t) complete (O's 12 newer remain)
    COMP(aE0,aE1,aE2,aE3,bE0h0,bE0h1,bE1h0,bE1h1,bE2h0,bE2h1,bE3h0,bE3h1);
    if (t + 2 < S){ ISSUE_E(); WAITV(12); } else { WAITV(0); }
    SBAR;
    COMP(aO0,aO1,aO2,aO3,bO0h0,bO0h1,bO1h0,bO1h1,bO2h0,bO2h1,bO3h0,bO3h1);
    if (t + 3 < S) ISSUE_O();
  }

  // ---- block reduction (the only barriers in the kernel) ----
  {
    int rr = (lane >> 4) << 2;
    int cc = lane & 15;
    lds[wid][rr+0][cc] = acc0[0]; lds[wid][rr+1][cc] = acc0[1];
    lds[wid][rr+2][cc] = acc0[2]; lds[wid][rr+3][cc] = acc0[3];
    lds[wid][rr+0][16+cc] = acc1[0]; lds[wid][rr+1][16+cc] = acc1[1];
    lds[wid][rr+2][16+cc] = acc1[2]; lds[wid][rr+3][16+cc] = acc1[3];
    lds[wid][rr+0][32+cc] = acc2[0]; lds[wid][rr+1][32+cc] = acc2[1];
    lds[wid][rr+2][32+cc] = acc2[2]; lds[wid][rr+3][32+cc] = acc2[3];
    lds[wid][rr+0][48+cc] = acc3[0]; lds[wid][rr+1][48+cc] = acc3[1];
    lds[wid][rr+2][48+cc] = acc3[2]; lds[wid][rr+3][48+cc] = acc3[3];
  }
  __syncthreads();
  {
    int row = tid >> 4;
    int c8  = (tid & 15) << 3;
    float v[8];
    #pragma unroll
    for (int i = 0; i < 8; ++i){
      int col = c8 + i;
      int w2  = (col >> 6) << 1;
      float s = lds[w2][row][col & 63] + lds[w2+1][row][col & 63];
      s *= j.scale;
      if (j.add) s += j.add[(size_t)(m0 + row)*128 + col];
      v[i] = s;
      fin[row][col] = s;
    }
    if (j.outF){
      float* dst = j.outF + (size_t)(m0 + row)*128 + c8;
      f32x4 v0 = {v[0],v[1],v[2],v[3]}, v1 = {v[4],v[5],v[6],v[7]};
      *(f32x4*)dst = v0; *((f32x4*)dst + 1) = v1;
    }
  }
  if (j.outT){
    __syncthreads();
    int col = tid >> 1, rg = (tid & 1) << 3;
    unsigned w[4] __attribute__((aligned(16)));
    #pragma unroll
    for (int r = 0; r < 4; ++r)
      w[r] = cvt2(fin[rg + 2*r][col], fin[rg + 2*r + 1][col]);
    bf16_t* dst = j.outT + (size_t)col * (size_t)j.outTstride + (m0 + rg);
    *(u32x4*)dst = *(const u32x4*)&w[0];
  }
}

// ================== gates GEMM (K=128) — verified round-1 structure ==================
#define GTBUF 24576

__global__ __launch_bounds__(256, 2) void gemm_gates(Job j0, Job j1, Job j2){
  __shared__ char smem[3*GTBUF];
  int bid = blockIdx.x;
  Job j = j0;
  if (bid >= j.nb){ bid -= j.nb; j = j1; if (bid >= j.nb){ bid -= j.nb; j = j2; } }
  const int K = j.K;
  const int T = K >> 6;
  const int m0 = bid << 5;
  const int tid = threadIdx.x;
  const int lane = tid & 63;
  const int wid = tid >> 6;
  const int wm = wid >> 1, wk = wid & 1;

  const char* Ab = (const char*)j.A;
  const char* Bb = (const char*)j.Bt;

  size_t a_src[2]; unsigned a_lds[2];
  #pragma unroll
  for (int i = 0; i < 2; ++i){
    int row = wid*8 + i*4 + (lane>>4);
    unsigned sb = (lane & 15) << 4;
    a_src[i] = (size_t)(m0 + row)*(size_t)K*4 + (size_t)(sb ^ ((row & 15) << 4));
    a_lds[i] = (unsigned)((wid*8 + i*4) * 256);
  }
  size_t b_src[4]; unsigned b_lds[4];
  #pragma unroll
  for (int i = 0; i < 4; ++i){
    int n  = wid*32 + i*8 + (lane>>3);
    unsigned sb = (lane & 7) << 4;
    b_src[i] = (size_t)n*(size_t)K*2 + (size_t)(sb ^ ((n & 7) << 4));
    b_lds[i] = (unsigned)(8192 + (wid*32 + i*8) * 128);
  }

  const int arow = wm*16 + (lane & 15);
  const unsigned acb  = (unsigned)(wk*128 + ((lane>>4) * 32));
  const unsigned aswz = (unsigned)((arow & 15) << 4);
  const unsigned a_rd0 = arow*256 + (acb ^ aswz);
  const unsigned a_rd1 = arow*256 + ((acb + 16) ^ aswz);
  unsigned b_rd[8];
  #pragma unroll
  for (int n0 = 0; n0 < 8; ++n0){
    int n = n0*16 + (lane & 15);
    unsigned c = (unsigned)(wk*64 + ((lane>>4) * 16));
    b_rd[n0] = 8192u + n*128 + (c ^ ((n & 7) << 4));
  }

  const f32x4 fzero = {0.f, 0.f, 0.f, 0.f};
  f32x4 acc[8];
  #pragma unroll
  for (int i = 0; i < 8; ++i) acc[i] = fzero;

  auto STAGE = [&](unsigned bufoff, int t){
    char* l = smem + bufoff;
    size_t ka = (size_t)t * 256;
    size_t kb = (size_t)t * 128;
    #pragma unroll
    for (int i = 0; i < 2; ++i) gload16(Ab + a_src[i] + ka, l + a_lds[i]);
    #pragma unroll
    for (int i = 0; i < 4; ++i) gload16(Bb + b_src[i] + kb, l + b_lds[i]);
  };

  STAGE(0, 0);
  if (T > 1){
    STAGE(GTBUF, 1);
    asm volatile("s_waitcnt vmcnt(6)" ::: "memory");
  } else {
    asm volatile("s_waitcnt vmcnt(0)" ::: "memory");
  }
  __builtin_amdgcn_s_barrier();

  for (int t = 0; t < T; ++t){
    char* l = smem + (unsigned)(t % 3) * GTBUF;
    if (t + 2 < T) STAGE((unsigned)((t+2) % 3) * GTBUF, t + 2);
    f32x4 a0 = *(const f32x4*)(l + a_rd0);
    f32x4 a1 = *(const f32x4*)(l + a_rd1);
    union { bf16x8 v; unsigned u[4]; } af;
    af.u[0] = cvt2(a0.x, a0.y);
    af.u[1] = cvt2(a0.z, a0.w);
    af.u[2] = cvt2(a1.x, a1.y);
    af.u[3] = cvt2(a1.z, a1.w);
    #pragma unroll
    for (int n0 = 0; n0 < 8; ++n0){
      bf16x8 bfr = *(const bf16x8*)(l + b_rd[n0]);
      acc[n0] = __builtin_amdgcn_mfma_f32_16x16x32_bf16(af.v, bfr, acc[n0], 0, 0, 0);
    }
    if (t + 1 < T){
      if (t + 2 < T) asm volatile("s_waitcnt vmcnt(6)" ::: "memory");
      else           asm volatile("s_waitcnt vmcnt(0)" ::: "memory");
      __builtin_amdgcn_s_barrier();
    }
  }

  __syncthreads();
  float* red = (float*)smem;
  if (wk == 1){
    #pragma unroll
    for (int n0 = 0; n0 < 8; ++n0)
      #pragma unroll
      for (int q = 0; q < 4; ++q){
        int row = wm*16 + ((lane>>4)<<2) + q;
        int col = n0*16 + (lane & 15);
        red[row*128 + col] = acc[n0][q];
      }
  }
  __syncthreads();
  if (wk == 0){
    #pragma unroll
    for (int n0 = 0; n0 < 8; ++n0)
      #pragma unroll
      for (int q = 0; q < 4; ++q){
        int row = wm*16 + ((lane>>4)<<2) + q;
        int col = n0*16 + (lane & 15);
        float v = (acc[n0][q] + red[row*128 + col]) * j.scale;
        size_t gp = (size_t)(m0 + row);
        if (j.mode == 1){
          float pe = j.add[gp*128 + col];
          float bb = j.bvec[col];
          v = pe / (1.f + __expf(-(v + bb)));
        } else if (j.add){
          v += j.add[gp*128 + col];
        }
        acc[n0][q] = v;
        if (j.outF) j.outF[gp*128 + col] = v;
      }
  }

  if (j.outT){
    __syncthreads();
    if (wk == 0){
      #pragma unroll
      for (int n0 = 0; n0 < 8; ++n0)
        #pragma unroll
        for (int q = 0; q < 4; ++q){
          int row = wm*16 + ((lane>>4)<<2) + q;
          int col = n0*16 + (lane & 15);
          red[row*128 + col] = acc[n0][q];
        }
    }
    __syncthreads();
    int col = tid & 127, seg = tid >> 7;
    unsigned wrds[8] __attribute__((aligned(16)));
    #pragma unroll
    for (int r = 0; r < 8; ++r){
      float v0 = red[(seg*16 + 2*r    )*128 + col];
      float v1 = red[(seg*16 + 2*r + 1)*128 + col];
      wrds[r] = cvt2(v0, v1);
    }
    bf16_t* dst = j.outT + (size_t)col * (size_t)j.outTstride + (m0 + seg*16);
    *(u32x4*)dst       = *(const u32x4*)&wrds[0];
    *((u32x4*)dst + 1) = *(const u32x4*)&wrds[4];
  }
}

// ---------------- gather GEMM (users), split-K=8, N=256 ----------------
#define GBUFB 40960

__global__ __launch_bounds__(256, 1) void gemm_gather(const float* __restrict__ Aup,
    const int* __restrict__ uidx, const bf16_t* __restrict__ B5t, float* __restrict__ partials){
  __shared__ char smem[3*GBUFB];
  const int bid = blockIdx.x;
  const int mtile = bid & 31, split = bid >> 5;
  const int tid = threadIdx.x, lane = tid & 63, wid = tid >> 6;
  const int wm = wid >> 1, wk = wid & 1;
  const int T = 16;
  const char* Ab = (const char*)Aup;
  const char* Bb = (const char*)B5t;

  size_t a_src[2]; unsigned a_lds[2];
  #pragma unroll
  for (int i = 0; i < 2; ++i){
    int row  = wid*8 + i*4 + (lane>>4);
    int grow = uidx[mtile*32 + row];
    unsigned sb = (lane & 15) << 4;
    a_src[i] = (size_t)grow*(size_t)(PP*4) + (size_t)((sb ^ ((row & 15) << 4)) + split*4096);
    a_lds[i] = (unsigned)((wid*8 + i*4) * 256);
  }
  size_t b_src[8]; unsigned b_lds[8];
  #pragma unroll
  for (int i = 0; i < 8; ++i){
    int n  = wid*64 + i*8 + (lane>>3);
    unsigned sb = (lane & 7) << 4;
    b_src[i] = (size_t)n*(size_t)(PP*2) + (size_t)((sb ^ ((n & 7) << 4)) + split*2048);
    b_lds[i] = (unsigned)(8192 + (wid*64 + i*8) * 128);
  }
  const int arow = wm*16 + (lane & 15);
  const unsigned acb  = (unsigned)(wk*128 + ((lane>>4)*32));
  const unsigned aswz = (unsigned)((arow & 15) << 4);
  const unsigned a_rd0 = arow*256 + (acb ^ aswz);
  const unsigned a_rd1 = arow*256 + ((acb + 16) ^ aswz);
  unsigned b_rd[16];
  #pragma unroll
  for (int n0 = 0; n0 < 16; ++n0){
    int n = n0*16 + (lane & 15);
    unsigned c = (unsigned)(wk*64 + ((lane>>4)*16));
    b_rd[n0] = 8192u + n*128 + (c ^ ((n & 7) << 4));
  }
  const f32x4 fzero = {0.f,0.f,0.f,0.f};
  f32x4 acc[16];
  #pragma unroll
  for (int i = 0; i < 16; ++i) acc[i] = fzero;

  auto STAGE = [&](unsigned bufoff, int t){
    char* l = smem + bufoff;
    size_t ka = (size_t)t*256, kb = (size_t)t*128;
    #pragma unroll
    for (int i = 0; i < 2; ++i) gload16(Ab + a_src[i] + ka, l + a_lds[i]);
    #pragma unroll
    for (int i = 0; i < 8; ++i) gload16(Bb + b_src[i] + kb, l + b_lds[i]);
  };
  STAGE(0, 0);
  STAGE(GBUFB, 1);
  asm volatile("s_waitcnt vmcnt(10)" ::: "memory");
  __builtin_amdgcn_s_barrier();
  for (int t = 0; t < T; ++t){
    char* l = smem + (unsigned)(t % 3) * GBUFB;
    if (t + 2 < T) STAGE((unsigned)((t+2)%3)*GBUFB, t+2);
    f32x4 a0 = *(const f32x4*)(l + a_rd0);
    f32x4 a1 = *(const f32x4*)(l + a_rd1);
    union { bf16x8 v; unsigned u[4]; } af;
    af.u[0] = cvt2(a0.x, a0.y);
    af.u[1] = cvt2(a0.z, a0.w);
    af.u[2] = cvt2(a1.x, a1.y);
    af.u[3] = cvt2(a1.z, a1.w);
    #pragma unroll
    for (int n0 = 0; n0 < 16; ++n0){
      bf16x8 bfr = *(const bf16x8*)(l + b_rd[n0]);
      acc[n0] = __builtin_amdgcn_mfma_f32_16x16x32_bf16(af.v, bfr, acc[n0], 0,0,0);
    }
    if (t + 1 < T){
      if (t + 2 < T) asm volatile("s_waitcnt vmcnt(10)" ::: "memory");
      else           asm volatile("s_waitcnt vmcnt(0)" ::: "memory");
      __builtin_amdgcn_s_barrier();
    }
  }
  __syncthreads();
  float* red = (float*)smem;
  if (wk == 1){
    #pragma unroll
    for (int n0 = 0; n0 < 16; ++n0)
      #pragma unroll
      for (int q = 0; q < 4; ++q){
        int row = wm*16 + ((lane>>4)<<2) + q;
        int col = n0*16 + (lane & 15);
        red[row*256 + col] = acc[n0][q];
      }
  }
  __syncthreads();
  if (wk == 0){
    #pragma unroll
    for (int n0 = 0; n0 < 16; ++n0)
      #pragma unroll
      for (int q = 0; q < 4; ++q){
        int row = wm*16 + ((lane>>4)<<2) + q;
        int col = n0*16 + (lane & 15);
        float v = acc[n0][q] + red[row*256 + col];
        partials[((size_t)split*1024 + mtile*32 + row)*256 + col] = v;
      }
  }
}

__global__ void prep_wt(const float* w0, const float* w1, const float* w2,
                        bf16_t* o0, bf16_t* o1, bf16_t* o2){
  const float* w = (blockIdx.x == 0) ? w0 : (blockIdx.x == 1) ? w1 : w2;
  bf16_t*      o = (blockIdx.x == 0) ? o0 : (blockIdx.x == 1) ? o1 : o2;
  int tid = threadIdx.x;
  int n = tid >> 1, h = tid & 1;
  unsigned wr[32] __attribute__((aligned(16)));
  #pragma unroll
  for (int r = 0; r < 32; ++r){
    float v0 = w[(h*64 + 2*r    )*128 + n];
    float v1 = w[(h*64 + 2*r + 1)*128 + n];
    wr[r] = cvt2(v0, v1);
  }
  u32x4* dst = (u32x4*)(o + n*128 + h*64);
  #pragma unroll
  for (int i = 0; i < 8; ++i) dst[i] = *(const u32x4*)&wr[i*4];
}

__global__ void reduce_users(const float* __restrict__ partials, float* __restrict__ out){
  int idx = blockIdx.x * 256 + threadIdx.x;
  int b = idx >> 8, n = idx & 255;
  float s = 0.f;
  #pragma unroll
  for (int k = 0; k < 8; ++k) s += partials[((size_t)k*1024 + b)*256 + n];
  if (n < 128) out[((size_t)(3*PP) + b)*128 + n]           = s;
  else         out[((size_t)(3*PP) + BB + b)*128 + (n-128)] = s;
}

extern "C" void kernel_launch(void* const* d_in, const int* in_sizes, int n_in,
                              void* d_out, int out_size, void* d_ws, size_t ws_size,
                              hipStream_t stream){
  const float* pe   = (const float*)d_in[0];
  const float* wgeo = (const float*)d_in[1];
  const float* bgeo = (const float*)d_in[2];
  const float* wseq = (const float*)d_in[3];
  const float* bseq = (const float*)d_in[4];
  const float* wcol = (const float*)d_in[5];
  const float* bcol = (const float*)d_in[6];
  const float* hup  = (const float*)d_in[7];
  const float* hpu  = (const float*)d_in[8];
  const float* hsrc = (const float*)d_in[9];
  const float* htar = (const float*)d_in[10];
  const float* geo  = (const float*)d_in[11];
  const int*   uidx = (const int*)d_in[12];
  float* out = (float*)d_out;

  char* w = (char*)d_ws;
  const size_t MB = 1024*1024;
  float*  x_f32 = (float*)(w);
  float*  g_f32 = (float*)(w + 4*MB);
  float*  s_f32 = (float*)(w + 8*MB);
  bf16_t* xT    = (bf16_t*)(w + 12*MB);
  bf16_t* gT    = (bf16_t*)(w + 14*MB);
  bf16_t* sT    = (bf16_t*)(w + 16*MB);
  bf16_t* upT   = (bf16_t*)(w + 18*MB);
  bf16_t* tarT  = (bf16_t*)(w + 19*MB);
  bf16_t* b5t   = (bf16_t*)(w + 20*MB);
  bf16_t* wtg   = (bf16_t*)(w + 24*MB);
  bf16_t* wts   = (bf16_t*)(w + 24*MB + 32768);
  bf16_t* wtc   = (bf16_t*)(w + 24*MB + 65536);
  float*  parts = (float*)(w + 25*MB);

  prep_wt<<<3, 256, 0, stream>>>(wgeo, wseq, wcol, wtg, wts, wtc);

  // gates: gate = pe * sigmoid(pe@W + b)
  Job jg{pe, wtg, pe, bgeo, g_f32, gT, PP, 1.f, 128, 256, 1};
  Job js{pe, wts, pe, bseq, s_f32, sT, PP, 1.f, 128, 256, 1};
  Job jc{pe, wtc, pe, bcol, x_f32, xT, PP, 1.f, 128, 256, 1};
  gemm_gates<<<768, 256, 0, stream>>>(jg, js, jc);

  // phase B: tmp_up = HG_up@x ; geo_pois = g + 0.4*(geo@g) ; tmp_tar = HG_poi_tar@s
  // (16-row tiles: nb = M/16)
  Job j1 {hup,  xT, nullptr, nullptr, nullptr,               upT,                  UU, 1.f,  PP, 256, 0};
  Job j3 {geo,  gT, g_f32,   nullptr, out + (size_t)PP*128,  b5t + (size_t)128*PP, PP, 0.4f, PP, 512, 0};
  Job j4a{htar, sT, nullptr, nullptr, nullptr,               tarT,                 EE, 1.f,  PP, 256, 0};
  gemm_stream<<<1024, 256, 0, stream>>>(j1, j3, j4a);

  // phase C: hg_pois = x + HG_pu@tmp_up ; trans_pois = s + src@tmp_tar
  // hpu: M=8192 -> 512 tiles; hsrc: M=8192 -> 512 tiles  (round-6 bug: was 256)
  Job j2 {hpu,  upT,  x_f32, nullptr, out,                     b5t,     PP, 1.f, UU, 512, 0};
  Job j4b{hsrc, tarT, s_f32, nullptr, out + (size_t)2*PP*128,  nullptr, 0,  1.f, EE, 512, 0};
  Job jd = j4b; jd.nb = 0;
  gemm_stream<<<1024, 256, 0, stream>>>(j2, j4b, jd);

  // users: HG_up[user_idx] @ [hg_pois | geo_pois], split-K=8 then deterministic reduce
  gemm_gather<<<256, 256, 0, stream>>>(hup, uidx, b5t, parts);
  reduce_users<<<1024, 256, 0, stream>>>(parts, out);
}

// Round 8
// 289.697 us; speedup vs baseline: 1.9633x; 1.9633x over previous
//
#include <hip/hip_runtime.h>
#include <hip/hip_bf16.h>

#define PP 8192
#define UU 4096
#define EE 4096
#define BB 1024

using f32x4  = __attribute__((ext_vector_type(4))) float;
using u32x4  = __attribute__((ext_vector_type(4))) unsigned int;
using bf16x8 = __attribute__((ext_vector_type(8))) short;
typedef __hip_bfloat16 bf16_t;

__device__ __forceinline__ unsigned cvt2(float a, float b){
  unsigned r;
  asm("v_cvt_pk_bf16_f32 %0, %1, %2" : "=v"(r) : "v"(a), "v"(b));
  return r;
}

__device__ __forceinline__ void gload16(const void* g, void* l){
  __builtin_amdgcn_global_load_lds((const __attribute__((address_space(1))) void*)g,
                                   (__attribute__((address_space(3))) void*)l, 16, 0, 0);
}

struct Job {
  const float*  A;      // [M][K] f32
  const bf16_t* Bt;     // [128][K] bf16 (B transposed)
  const float*  add;    // epilogue add (or pe for sigmoid mode); may be null
  const float*  bvec;   // sigmoid bias [128]; null otherwise
  float*        outF;   // f32 out [M][128]; may be null
  bf16_t*       outT;   // transposed bf16 out [128][stride]; may be null
  int           outTstride;
  float         scale;  // final = add + scale*C   (mode 0)
  int           K;
  int           nb;     // number of 32-row blocks
  int           mode;   // 0 linear, 1 sigmoid-gate
};

#define WAITV(n) asm volatile("s_waitcnt vmcnt(" #n ")" ::: "memory")
#define LGKM0    asm volatile("s_waitcnt lgkmcnt(0)" ::: "memory")
#define SBAR     __builtin_amdgcn_sched_barrier(0)
#define BAR      __builtin_amdgcn_s_barrier()

// ============ REG-STAGED GEMM: plain loads -> regs -> ds_write (no global_load_lds) ============
// BM=32, BK=64, 256 thr = 4 waves (wm2 x wk2). 2 x 24KB LDS buffers.
// Staging: thread t owns row t>>3, bytes (t&7)*16 -> contiguous 256B runs per instruction.
#define RSBUF 24576

__global__ __launch_bounds__(256, 2) void gemm_rs(Job j0, Job j1, Job j2){
  __shared__ char smem[2*RSBUF];
  int bid = blockIdx.x;
  Job j = j0;
  if (bid >= j.nb){ bid -= j.nb; j = j1; if (bid >= j.nb){ bid -= j.nb; j = j2; } }
  const int K = j.K;
  const int T = K >> 6;                 // even (64 or 128)
  const int m0 = bid << 5;
  const int tid = threadIdx.x;
  const int lane = tid & 63;
  const int wid = tid >> 6;
  const int wm = wid >> 1, wk = wid & 1;

  // ---- staging source pointers (contiguous 256B per instr across 8 lanes) ----
  const int srow = tid >> 3;            // 0..31
  const int scol = (tid & 7) * 16;      // 0..112
  const char* ap  = (const char*)j.A  + (size_t)(m0 + srow)*(size_t)K*4 + (unsigned)scol;
  const char* bq0 = (const char*)j.Bt + (size_t)(srow      )*(size_t)K*2 + (unsigned)scol;
  const char* bq1 = (const char*)j.Bt + (size_t)(srow +  32)*(size_t)K*2 + (unsigned)scol;
  const char* bq2 = (const char*)j.Bt + (size_t)(srow +  64)*(size_t)K*2 + (unsigned)scol;
  const char* bq3 = (const char*)j.Bt + (size_t)(srow +  96)*(size_t)K*2 + (unsigned)scol;

  // ---- LDS write addresses: LDS[row*stride + (g ^ swz)] = glob[g]  (same layout as R1) ----
  const unsigned aswzw = (unsigned)((srow & 15) << 4);
  const unsigned wa0 = (unsigned)(srow*256) + ((unsigned)scol ^ aswzw);
  const unsigned wa1 = (unsigned)(srow*256) + (((unsigned)scol + 128u) ^ aswzw);
  const unsigned bswzw = (unsigned)((srow & 7) << 4);
  const unsigned wb0 = 8192u + (unsigned)(srow*128) + ((unsigned)scol ^ bswzw);
  // B rows +32/+64/+96 -> +4096/+8192/+12288 (srow&7 unchanged -> same swizzle)

  // ---- fragment read addresses (identical to round-1 verified layout) ----
  const int arow = wm*16 + (lane & 15);
  const unsigned acb  = (unsigned)(wk*128 + ((lane>>4) * 32));
  const unsigned aswz = (unsigned)((arow & 15) << 4);
  const unsigned a_rd0 = arow*256 + (acb ^ aswz);
  const unsigned a_rd1 = arow*256 + ((acb + 16) ^ aswz);
  unsigned b_rd[8];
  #pragma unroll
  for (int n0 = 0; n0 < 8; ++n0){
    int n = n0*16 + (lane & 15);
    unsigned c = (unsigned)(wk*64 + ((lane>>4) * 16));
    b_rd[n0] = 8192u + n*128 + (c ^ ((n & 7) << 4));
  }

  f32x4 acc[8];
  const f32x4 fzero = {0.f,0.f,0.f,0.f};
  #pragma unroll
  for (int i = 0; i < 8; ++i) acc[i] = fzero;

  // two static register sets (E/O)
  f32x4 eA0,eA1,eB0,eB1,eB2,eB3, oA0,oA1,oB0,oB1,oB2,oB3;

#define RS_ISSUE(A0,A1,B0,B1,B2,B3) do { \
    asm volatile("global_load_dwordx4 %0, %2, off\n\t" \
                 "global_load_dwordx4 %1, %2, off offset:128" \
      : "=&v"(A0), "=&v"(A1) : "v"(ap) : "memory"); \
    asm volatile("global_load_dwordx4 %0, %1, off" : "=&v"(B0) : "v"(bq0) : "memory"); \
    asm volatile("global_load_dwordx4 %0, %1, off" : "=&v"(B1) : "v"(bq1) : "memory"); \
    asm volatile("global_load_dwordx4 %0, %1, off" : "=&v"(B2) : "v"(bq2) : "memory"); \
    asm volatile("global_load_dwordx4 %0, %1, off" : "=&v"(B3) : "v"(bq3) : "memory"); \
    ap += 256; bq0 += 128; bq1 += 128; bq2 += 128; bq3 += 128; } while(0)

#define RS_DSW(bo,A0,A1,B0,B1,B2,B3) do { \
    asm volatile("ds_write_b128 %0, %1" :: "v"((bo) + wa0), "v"(A0) : "memory"); \
    asm volatile("ds_write_b128 %0, %1" :: "v"((bo) + wa1), "v"(A1) : "memory"); \
    asm volatile("ds_write_b128 %0, %1"              :: "v"((bo) + wb0), "v"(B0) : "memory"); \
    asm volatile("ds_write_b128 %0, %1 offset:4096"  :: "v"((bo) + wb0), "v"(B1) : "memory"); \
    asm volatile("ds_write_b128 %0, %1 offset:8192"  :: "v"((bo) + wb0), "v"(B2) : "memory"); \
    asm volatile("ds_write_b128 %0, %1 offset:12288" :: "v"((bo) + wb0), "v"(B3) : "memory"); } while(0)

  auto COMP = [&](unsigned bo){
    f32x4 a0, a1;
    asm volatile("ds_read_b128 %0, %1" : "=v"(a0) : "v"(bo + a_rd0));
    asm volatile("ds_read_b128 %0, %1" : "=v"(a1) : "v"(bo + a_rd1));
    bf16x8 b0,b1,b2,b3,b4,b5,b6,b7;
    asm volatile("ds_read_b128 %0, %1" : "=v"(b0) : "v"(bo + b_rd[0]));
    asm volatile("ds_read_b128 %0, %1" : "=v"(b1) : "v"(bo + b_rd[1]));
    asm volatile("ds_read_b128 %0, %1" : "=v"(b2) : "v"(bo + b_rd[2]));
    asm volatile("ds_read_b128 %0, %1" : "=v"(b3) : "v"(bo + b_rd[3]));
    asm volatile("ds_read_b128 %0, %1" : "=v"(b4) : "v"(bo + b_rd[4]));
    asm volatile("ds_read_b128 %0, %1" : "=v"(b5) : "v"(bo + b_rd[5]));
    asm volatile("ds_read_b128 %0, %1" : "=v"(b6) : "v"(bo + b_rd[6]));
    asm volatile("ds_read_b128 %0, %1" : "=v"(b7) : "v"(bo + b_rd[7]));
    LGKM0;
    SBAR;                                 // rule #18
    union { bf16x8 v; unsigned u[4]; } af;
    af.u[0] = cvt2(a0.x, a0.y);
    af.u[1] = cvt2(a0.z, a0.w);
    af.u[2] = cvt2(a1.x, a1.y);
    af.u[3] = cvt2(a1.z, a1.w);
    acc[0] = __builtin_amdgcn_mfma_f32_16x16x32_bf16(af.v, b0, acc[0], 0,0,0);
    acc[1] = __builtin_amdgcn_mfma_f32_16x16x32_bf16(af.v, b1, acc[1], 0,0,0);
    acc[2] = __builtin_amdgcn_mfma_f32_16x16x32_bf16(af.v, b2, acc[2], 0,0,0);
    acc[3] = __builtin_amdgcn_mfma_f32_16x16x32_bf16(af.v, b3, acc[3], 0,0,0);
    acc[4] = __builtin_amdgcn_mfma_f32_16x16x32_bf16(af.v, b4, acc[4], 0,0,0);
    acc[5] = __builtin_amdgcn_mfma_f32_16x16x32_bf16(af.v, b5, acc[5], 0,0,0);
    acc[6] = __builtin_amdgcn_mfma_f32_16x16x32_bf16(af.v, b6, acc[6], 0,0,0);
    acc[7] = __builtin_amdgcn_mfma_f32_16x16x32_bf16(af.v, b7, acc[7], 0,0,0);
  };

  // prologue: stages 0 (E) and 1 (O) in flight; write stage 0
  RS_ISSUE(eA0,eA1,eB0,eB1,eB2,eB3);
  RS_ISSUE(oA0,oA1,oB0,oB1,oB2,oB3);
  WAITV(6);
  RS_DSW(0u, eA0,eA1,eB0,eB1,eB2,eB3);
  LGKM0; BAR;

  for (int t = 0; t < T; t += 2){
    // ---- even step: compute stage t from buf0; O(t+1) lands; E reloads t+2 ----
    if (t + 2 < T) RS_ISSUE(eA0,eA1,eB0,eB1,eB2,eB3);
    COMP(0u);
    if (t + 2 < T) WAITV(6); else WAITV(0);
    RS_DSW(RSBUF, oA0,oA1,oB0,oB1,oB2,oB3);
    LGKM0; BAR;
    // ---- odd step: compute stage t+1 from buf1; E(t+2) lands; O reloads t+3 ----
    if (t + 3 < T) RS_ISSUE(oA0,oA1,oB0,oB1,oB2,oB3);
    COMP(RSBUF);
    if (t + 2 < T){
      if (t + 3 < T) WAITV(6); else WAITV(0);
      RS_DSW(0u, eA0,eA1,eB0,eB1,eB2,eB3);
      LGKM0; BAR;
    }
  }

  // ---- K-split (wk) reduction via LDS (round-1 verified epilogue) ----
  __syncthreads();
  float* red = (float*)smem;
  if (wk == 1){
    #pragma unroll
    for (int n0 = 0; n0 < 8; ++n0)
      #pragma unroll
      for (int q = 0; q < 4; ++q){
        int row = wm*16 + ((lane>>4)<<2) + q;
        int col = n0*16 + (lane & 15);
        red[row*128 + col] = acc[n0][q];
      }
  }
  __syncthreads();
  if (wk == 0){
    #pragma unroll
    for (int n0 = 0; n0 < 8; ++n0)
      #pragma unroll
      for (int q = 0; q < 4; ++q){
        int row = wm*16 + ((lane>>4)<<2) + q;
        int col = n0*16 + (lane & 15);
        float v = (acc[n0][q] + red[row*128 + col]) * j.scale;
        size_t gp = (size_t)(m0 + row);
        if (j.mode == 1){
          float pe = j.add[gp*128 + col];
          float bb = j.bvec[col];
          v = pe / (1.f + __expf(-(v + bb)));
        } else if (j.add){
          v += j.add[gp*128 + col];
        }
        acc[n0][q] = v;
        if (j.outF) j.outF[gp*128 + col] = v;
      }
  }

  if (j.outT){
    __syncthreads();
    if (wk == 0){
      #pragma unroll
      for (int n0 = 0; n0 < 8; ++n0)
        #pragma unroll
        for (int q = 0; q < 4; ++q){
          int row = wm*16 + ((lane>>4)<<2) + q;
          int col = n0*16 + (lane & 15);
          red[row*128 + col] = acc[n0][q];
        }
    }
    __syncthreads();
    int col = tid & 127, seg = tid >> 7;   // 2 segs x 16 rows
    unsigned wrds[8] __attribute__((aligned(16)));
    #pragma unroll
    for (int r = 0; r < 8; ++r){
      float v0 = red[(seg*16 + 2*r    )*128 + col];
      float v1 = red[(seg*16 + 2*r + 1)*128 + col];
      wrds[r] = cvt2(v0, v1);
    }
    bf16_t* dst = j.outT + (size_t)col * (size_t)j.outTstride + (m0 + seg*16);
    *(u32x4*)dst       = *(const u32x4*)&wrds[0];
    *((u32x4*)dst + 1) = *(const u32x4*)&wrds[4];
  }
}

// ================== gates GEMM (K=128) — round-1 verified ==================
#define GTBUF 24576

__global__ __launch_bounds__(256, 2) void gemm_gates(Job j0, Job j1, Job j2){
  __shared__ char smem[3*GTBUF];
  int bid = blockIdx.x;
  Job j = j0;
  if (bid >= j.nb){ bid -= j.nb; j = j1; if (bid >= j.nb){ bid -= j.nb; j = j2; } }
  const int K = j.K;
  const int T = K >> 6;
  const int m0 = bid << 5;
  const int tid = threadIdx.x;
  const int lane = tid & 63;
  const int wid = tid >> 6;
  const int wm = wid >> 1, wk = wid & 1;

  const char* Ab = (const char*)j.A;
  const char* Bb = (const char*)j.Bt;

  size_t a_src[2]; unsigned a_lds[2];
  #pragma unroll
  for (int i = 0; i < 2; ++i){
    int row = wid*8 + i*4 + (lane>>4);
    unsigned sb = (lane & 15) << 4;
    a_src[i] = (size_t)(m0 + row)*(size_t)K*4 + (size_t)(sb ^ ((row & 15) << 4));
    a_lds[i] = (unsigned)((wid*8 + i*4) * 256);
  }
  size_t b_src[4]; unsigned b_lds[4];
  #pragma unroll
  for (int i = 0; i < 4; ++i){
    int n  = wid*32 + i*8 + (lane>>3);
    unsigned sb = (lane & 7) << 4;
    b_src[i] = (size_t)n*(size_t)K*2 + (size_t)(sb ^ ((n & 7) << 4));
    b_lds[i] = (unsigned)(8192 + (wid*32 + i*8) * 128);
  }

  const int arow = wm*16 + (lane & 15);
  const unsigned acb  = (unsigned)(wk*128 + ((lane>>4) * 32));
  const unsigned aswz = (unsigned)((arow & 15) << 4);
  const unsigned a_rd0 = arow*256 + (acb ^ aswz);
  const unsigned a_rd1 = arow*256 + ((acb + 16) ^ aswz);
  unsigned b_rd[8];
  #pragma unroll
  for (int n0 = 0; n0 < 8; ++n0){
    int n = n0*16 + (lane & 15);
    unsigned c = (unsigned)(wk*64 + ((lane>>4) * 16));
    b_rd[n0] = 8192u + n*128 + (c ^ ((n & 7) << 4));
  }

  const f32x4 fzero = {0.f, 0.f, 0.f, 0.f};
  f32x4 acc[8];
  #pragma unroll
  for (int i = 0; i < 8; ++i) acc[i] = fzero;

  auto STAGE = [&](unsigned bufoff, int t){
    char* l = smem + bufoff;
    size_t ka = (size_t)t * 256;
    size_t kb = (size_t)t * 128;
    #pragma unroll
    for (int i = 0; i < 2; ++i) gload16(Ab + a_src[i] + ka, l + a_lds[i]);
    #pragma unroll
    for (int i = 0; i < 4; ++i) gload16(Bb + b_src[i] + kb, l + b_lds[i]);
  };

  STAGE(0, 0);
  if (T > 1){
    STAGE(GTBUF, 1);
    asm volatile("s_waitcnt vmcnt(6)" ::: "memory");
  } else {
    asm volatile("s_waitcnt vmcnt(0)" ::: "memory");
  }
  __builtin_amdgcn_s_barrier();

  for (int t = 0; t < T; ++t){
    char* l = smem + (unsigned)(t % 3) * GTBUF;
    if (t + 2 < T) STAGE((unsigned)((t+2) % 3) * GTBUF, t + 2);
    f32x4 a0 = *(const f32x4*)(l + a_rd0);
    f32x4 a1 = *(const f32x4*)(l + a_rd1);
    union { bf16x8 v; unsigned u[4]; } af;
    af.u[0] = cvt2(a0.x, a0.y);
    af.u[1] = cvt2(a0.z, a0.w);
    af.u[2] = cvt2(a1.x, a1.y);
    af.u[3] = cvt2(a1.z, a1.w);
    #pragma unroll
    for (int n0 = 0; n0 < 8; ++n0){
      bf16x8 bfr = *(const bf16x8*)(l + b_rd[n0]);
      acc[n0] = __builtin_amdgcn_mfma_f32_16x16x32_bf16(af.v, bfr, acc[n0], 0, 0, 0);
    }
    if (t + 1 < T){
      if (t + 2 < T) asm volatile("s_waitcnt vmcnt(6)" ::: "memory");
      else           asm volatile("s_waitcnt vmcnt(0)" ::: "memory");
      __builtin_amdgcn_s_barrier();
    }
  }

  __syncthreads();
  float* red = (float*)smem;
  if (wk == 1){
    #pragma unroll
    for (int n0 = 0; n0 < 8; ++n0)
      #pragma unroll
      for (int q = 0; q < 4; ++q){
        int row = wm*16 + ((lane>>4)<<2) + q;
        int col = n0*16 + (lane & 15);
        red[row*128 + col] = acc[n0][q];
      }
  }
  __syncthreads();
  if (wk == 0){
    #pragma unroll
    for (int n0 = 0; n0 < 8; ++n0)
      #pragma unroll
      for (int q = 0; q < 4; ++q){
        int row = wm*16 + ((lane>>4)<<2) + q;
        int col = n0*16 + (lane & 15);
        float v = (acc[n0][q] + red[row*128 + col]) * j.scale;
        size_t gp = (size_t)(m0 + row);
        if (j.mode == 1){
          float pe = j.add[gp*128 + col];
          float bb = j.bvec[col];
          v = pe / (1.f + __expf(-(v + bb)));
        } else if (j.add){
          v += j.add[gp*128 + col];
        }
        acc[n0][q] = v;
        if (j.outF) j.outF[gp*128 + col] = v;
      }
  }

  if (j.outT){
    __syncthreads();
    if (wk == 0){
      #pragma unroll
      for (int n0 = 0; n0 < 8; ++n0)
        #pragma unroll
        for (int q = 0; q < 4; ++q){
          int row = wm*16 + ((lane>>4)<<2) + q;
          int col = n0*16 + (lane & 15);
          red[row*128 + col] = acc[n0][q];
        }
    }
    __syncthreads();
    int col = tid & 127, seg = tid >> 7;
    unsigned wrds[8] __attribute__((aligned(16)));
    #pragma unroll
    for (int r = 0; r < 8; ++r){
      float v0 = red[(seg*16 + 2*r    )*128 + col];
      float v1 = red[(seg*16 + 2*r + 1)*128 + col];
      wrds[r] = cvt2(v0, v1);
    }
    bf16_t* dst = j.outT + (size_t)col * (size_t)j.outTstride + (m0 + seg*16);
    *(u32x4*)dst       = *(const u32x4*)&wrds[0];
    *((u32x4*)dst + 1) = *(const u32x4*)&wrds[4];
  }
}

// ---------------- gather GEMM (users), split-K=8, N=256 ----------------
#define GBUFB 40960

__global__ __launch_bounds__(256, 1) void gemm_gather(const float* __restrict__ Aup,
    const int* __restrict__ uidx, const bf16_t* __restrict__ B5t, float* __restrict__ partials){
  __shared__ char smem[3*GBUFB];
  const int bid = blockIdx.x;
  const int mtile = bid & 31, split = bid >> 5;
  const int tid = threadIdx.x, lane = tid & 63, wid = tid >> 6;
  const int wm = wid >> 1, wk = wid & 1;
  const int T = 16;
  const char* Ab = (const char*)Aup;
  const char* Bb = (const char*)B5t;

  size_t a_src[2]; unsigned a_lds[2];
  #pragma unroll
  for (int i = 0; i < 2; ++i){
    int row  = wid*8 + i*4 + (lane>>4);
    int grow = uidx[mtile*32 + row];
    unsigned sb = (lane & 15) << 4;
    a_src[i] = (size_t)grow*(size_t)(PP*4) + (size_t)((sb ^ ((row & 15) << 4)) + split*4096);
    a_lds[i] = (unsigned)((wid*8 + i*4) * 256);
  }
  size_t b_src[8]; unsigned b_lds[8];
  #pragma unroll
  for (int i = 0; i < 8; ++i){
    int n  = wid*64 + i*8 + (lane>>3);
    unsigned sb = (lane & 7) << 4;
    b_src[i] = (size_t)n*(size_t)(PP*2) + (size_t)((sb ^ ((n & 7) << 4)) + split*2048);
    b_lds[i] = (unsigned)(8192 + (wid*64 + i*8) * 128);
  }
  const int arow = wm*16 + (lane & 15);
  const unsigned acb  = (unsigned)(wk*128 + ((lane>>4)*32));
  const unsigned aswz = (unsigned)((arow & 15) << 4);
  const unsigned a_rd0 = arow*256 + (acb ^ aswz);
  const unsigned a_rd1 = arow*256 + ((acb + 16) ^ aswz);
  unsigned b_rd[16];
  #pragma unroll
  for (int n0 = 0; n0 < 16; ++n0){
    int n = n0*16 + (lane & 15);
    unsigned c = (unsigned)(wk*64 + ((lane>>4)*16));
    b_rd[n0] = 8192u + n*128 + (c ^ ((n & 7) << 4));
  }
  const f32x4 fzero = {0.f,0.f,0.f,0.f};
  f32x4 acc[16];
  #pragma unroll
  for (int i = 0; i < 16; ++i) acc[i] = fzero;

  auto STAGE = [&](unsigned bufoff, int t){
    char* l = smem + bufoff;
    size_t ka = (size_t)t*256, kb = (size_t)t*128;
    #pragma unroll
    for (int i = 0; i < 2; ++i) gload16(Ab + a_src[i] + ka, l + a_lds[i]);
    #pragma unroll
    for (int i = 0; i < 8; ++i) gload16(Bb + b_src[i] + kb, l + b_lds[i]);
  };
  STAGE(0, 0);
  STAGE(GBUFB, 1);
  asm volatile("s_waitcnt vmcnt(10)" ::: "memory");
  __builtin_amdgcn_s_barrier();
  for (int t = 0; t < T; ++t){
    char* l = smem + (unsigned)(t % 3) * GBUFB;
    if (t + 2 < T) STAGE((unsigned)((t+2)%3)*GBUFB, t+2);
    f32x4 a0 = *(const f32x4*)(l + a_rd0);
    f32x4 a1 = *(const f32x4*)(l + a_rd1);
    union { bf16x8 v; unsigned u[4]; } af;
    af.u[0] = cvt2(a0.x, a0.y);
    af.u[1] = cvt2(a0.z, a0.w);
    af.u[2] = cvt2(a1.x, a1.y);
    af.u[3] = cvt2(a1.z, a1.w);
    #pragma unroll
    for (int n0 = 0; n0 < 16; ++n0){
      bf16x8 bfr = *(const bf16x8*)(l + b_rd[n0]);
      acc[n0] = __builtin_amdgcn_mfma_f32_16x16x32_bf16(af.v, bfr, acc[n0], 0,0,0);
    }
    if (t + 1 < T){
      if (t + 2 < T) asm volatile("s_waitcnt vmcnt(10)" ::: "memory");
      else           asm volatile("s_waitcnt vmcnt(0)" ::: "memory");
      __builtin_amdgcn_s_barrier();
    }
  }
  __syncthreads();
  float* red = (float*)smem;
  if (wk == 1){
    #pragma unroll
    for (int n0 = 0; n0 < 16; ++n0)
      #pragma unroll
      for (int q = 0; q < 4; ++q){
        int row = wm*16 + ((lane>>4)<<2) + q;
        int col = n0*16 + (lane & 15);
        red[row*256 + col] = acc[n0][q];
      }
  }
  __syncthreads();
  if (wk == 0){
    #pragma unroll
    for (int n0 = 0; n0 < 16; ++n0)
      #pragma unroll
      for (int q = 0; q < 4; ++q){
        int row = wm*16 + ((lane>>4)<<2) + q;
        int col = n0*16 + (lane & 15);
        float v = acc[n0][q] + red[row*256 + col];
        partials[((size_t)split*1024 + mtile*32 + row)*256 + col] = v;
      }
  }
}

__global__ void prep_wt(const float* w0, const float* w1, const float* w2,
                        bf16_t* o0, bf16_t* o1, bf16_t* o2){
  const float* w = (blockIdx.x == 0) ? w0 : (blockIdx.x == 1) ? w1 : w2;
  bf16_t*      o = (blockIdx.x == 0) ? o0 : (blockIdx.x == 1) ? o1 : o2;
  int tid = threadIdx.x;
  int n = tid >> 1, h = tid & 1;
  unsigned wr[32] __attribute__((aligned(16)));
  #pragma unroll
  for (int r = 0; r < 32; ++r){
    float v0 = w[(h*64 + 2*r    )*128 + n];
    float v1 = w[(h*64 + 2*r + 1)*128 + n];
    wr[r] = cvt2(v0, v1);
  }
  u32x4* dst = (u32x4*)(o + n*128 + h*64);
  #pragma unroll
  for (int i = 0; i < 8; ++i) dst[i] = *(const u32x4*)&wr[i*4];
}

__global__ void reduce_users(const float* __restrict__ partials, float* __restrict__ out){
  int idx = blockIdx.x * 256 + threadIdx.x;
  int b = idx >> 8, n = idx & 255;
  float s = 0.f;
  #pragma unroll
  for (int k = 0; k < 8; ++k) s += partials[((size_t)k*1024 + b)*256 + n];
  if (n < 128) out[((size_t)(3*PP) + b)*128 + n]           = s;
  else         out[((size_t)(3*PP) + BB + b)*128 + (n-128)] = s;
}

extern "C" void kernel_launch(void* const* d_in, const int* in_sizes, int n_in,
                              void* d_out, int out_size, void* d_ws, size_t ws_size,
                              hipStream_t stream){
  const float* pe   = (const float*)d_in[0];
  const float* wgeo = (const float*)d_in[1];
  const float* bgeo = (const float*)d_in[2];
  const float* wseq = (const float*)d_in[3];
  const float* bseq = (const float*)d_in[4];
  const float* wcol = (const float*)d_in[5];
  const float* bcol = (const float*)d_in[6];
  const float* hup  = (const float*)d_in[7];
  const float* hpu  = (const float*)d_in[8];
  const float* hsrc = (const float*)d_in[9];
  const float* htar = (const float*)d_in[10];
  const float* geo  = (const float*)d_in[11];
  const int*   uidx = (const int*)d_in[12];
  float* out = (float*)d_out;

  char* w = (char*)d_ws;
  const size_t MB = 1024*1024;
  float*  x_f32 = (float*)(w);
  float*  g_f32 = (float*)(w + 4*MB);
  float*  s_f32 = (float*)(w + 8*MB);
  bf16_t* xT    = (bf16_t*)(w + 12*MB);
  bf16_t* gT    = (bf16_t*)(w + 14*MB);
  bf16_t* sT    = (bf16_t*)(w + 16*MB);
  bf16_t* upT   = (bf16_t*)(w + 18*MB);
  bf16_t* tarT  = (bf16_t*)(w + 19*MB);
  bf16_t* b5t   = (bf16_t*)(w + 20*MB);
  bf16_t* wtg   = (bf16_t*)(w + 24*MB);
  bf16_t* wts   = (bf16_t*)(w + 24*MB + 32768);
  bf16_t* wtc   = (bf16_t*)(w + 24*MB + 65536);
  float*  parts = (float*)(w + 25*MB);

  prep_wt<<<3, 256, 0, stream>>>(wgeo, wseq, wcol, wtg, wts, wtc);

  // gates: gate = pe * sigmoid(pe@W + b)
  Job jg{pe, wtg, pe, bgeo, g_f32, gT, PP, 1.f, 128, 256, 1};
  Job js{pe, wts, pe, bseq, s_f32, sT, PP, 1.f, 128, 256, 1};
  Job jc{pe, wtc, pe, bcol, x_f32, xT, PP, 1.f, 128, 256, 1};
  gemm_gates<<<768, 256, 0, stream>>>(jg, js, jc);

  // phase B: tmp_up = HG_up@x ; geo_pois = g + 0.4*(geo@g) ; tmp_tar = HG_poi_tar@s
  Job j1 {hup,  xT, nullptr, nullptr, nullptr,               upT,                  UU, 1.f,  PP, 128, 0};
  Job j3 {geo,  gT, g_f32,   nullptr, out + (size_t)PP*128,  b5t + (size_t)128*PP, PP, 0.4f, PP, 256, 0};
  Job j4a{htar, sT, nullptr, nullptr, nullptr,               tarT,                 EE, 1.f,  PP, 128, 0};
  gemm_rs<<<512, 256, 0, stream>>>(j1, j3, j4a);

  // phase C: hg_pois = x + HG_pu@tmp_up ; trans_pois = s + src@tmp_tar
  Job j2 {hpu,  upT,  x_f32, nullptr, out,                     b5t,     PP, 1.f, UU, 256, 0};
  Job j4b{hsrc, tarT, s_f32, nullptr, out + (size_t)2*PP*128,  nullptr, 0,  1.f, EE, 256, 0};
  Job jd = j4b; jd.nb = 0;
  gemm_rs<<<512, 256, 0, stream>>>(j2, j4b, jd);

  // users: HG_up[user_idx] @ [hg_pois | geo_pois], split-K=8 then deterministic reduce
  gemm_gather<<<256, 256, 0, stream>>>(hup, uidx, b5t, parts);
  reduce_users<<<1024, 256, 0, stream>>>(parts, out);
}